// Round 5
// baseline (220.523 us; speedup 1.0000x reference)
//
#include <hip/hip_runtime.h>
#include <hip/hip_bf16.h>

// out = elu(segment_sum(typed_linear(x[src], W_w, etype), dst) + x@W_res + b_res)
// (attention path of the reference is dead code)
//
// y = x @ [W_0..W_7, W_res]  ([N,128]x[128,1152] dense MFMA GEMM), then
// out[n] = elu(sum_{e: dst=n} y[src[e], et*128..] + y[n,1024..] + b_res).
// CSR over dst via two-pass LDS counting sort (128-node buckets).

#define KW 1152     // 9*128 columns of y (8 types + residual)
#define CAP 3072    // per-bucket capacity (mean ~2046, ~+22 sigma)
#define CHUNK 2048  // edges per binning block

typedef __bf16 bf16x8 __attribute__((ext_vector_type(8)));
typedef float f32x4 __attribute__((ext_vector_type(4)));
typedef float f32x2 __attribute__((ext_vector_type(2)));

__device__ __forceinline__ void gload_lds16(const void* g, void* l) {
  __builtin_amdgcn_global_load_lds(
      (const __attribute__((address_space(1))) unsigned int*)g,
      (__attribute__((address_space(3))) unsigned int*)l, 16, 0, 0);
}

// ---------------- CSR pass A: coarse binning by dst>>7 ----------------
// pack26 = (src<<10) | (et<<7) | (dst&127)   (src < 65536, et < 8)
__global__ __launch_bounds__(512) void k_binA(
    const int* __restrict__ src, const int* __restrict__ dst,
    const int* __restrict__ et, int* __restrict__ gCount,
    int* __restrict__ bucketBuf, int E) {
  __shared__ int buf[CHUNK];
  __shared__ short bkt[CHUNK];
  __shared__ int hist[512], sc[512], ls[512], cur[512], gb[512];
  const int tid = threadIdx.x;
  const int base = blockIdx.x * CHUNK;
  const int cnt = min(CHUNK, E - base);

  hist[tid] = 0;
  __syncthreads();
  for (int j = tid; j < cnt; j += 512) atomicAdd(&hist[dst[base + j] >> 7], 1);
  __syncthreads();
  sc[tid] = hist[tid];
  __syncthreads();
  for (int off = 1; off < 512; off <<= 1) {
    int t = (tid >= off) ? sc[tid - off] : 0;
    __syncthreads();
    if (tid >= off) sc[tid] += t;
    __syncthreads();
  }
  ls[tid] = sc[tid] - hist[tid];
  cur[tid] = ls[tid];
  gb[tid] = (hist[tid] > 0) ? atomicAdd(&gCount[tid], hist[tid]) : 0;
  __syncthreads();
  for (int j = tid; j < cnt; j += 512) {
    int e = base + j;
    int d = dst[e];
    int b = d >> 7;
    int pos = atomicAdd(&cur[b], 1);
    buf[pos] = (src[e] << 10) | (et[e] << 7) | (d & 127);
    bkt[pos] = (short)b;
  }
  __syncthreads();
  // bucket-grouped LDS order -> run-wise coalesced global writes
  for (int j = tid; j < cnt; j += 512) {
    int b = bkt[j];
    bucketBuf[b * CAP + gb[b] + (j - ls[b])] = buf[j];
  }
}

// exclusive scan of coarse counts; also rowstart[N] = E
__global__ __launch_bounds__(512) void k_scanC(
    const int* __restrict__ gCount, int* __restrict__ coarseBase,
    int* __restrict__ rowstart, int N, int E) {
  __shared__ int sc[512], h[512];
  int tid = threadIdx.x;
  h[tid] = gCount[tid];
  sc[tid] = h[tid];
  __syncthreads();
  for (int off = 1; off < 512; off <<= 1) {
    int t = (tid >= off) ? sc[tid - off] : 0;
    __syncthreads();
    if (tid >= off) sc[tid] += t;
    __syncthreads();
  }
  coarseBase[tid] = sc[tid] - h[tid];
  if (tid == 0) rowstart[N] = E;
}

// ---------------- CSR pass B: fine sort by dst&127 in LDS ----------------
__global__ __launch_bounds__(512) void k_sortB(
    const int* __restrict__ bucketBuf, const int* __restrict__ gCount,
    const int* __restrict__ coarseBase, int* __restrict__ rowstart,
    int* __restrict__ packed, int N) {
  __shared__ int raw[CAP];
  __shared__ int srt[CAP];
  __shared__ int hist[128], sc[128], bs[128], cur[128];
  const int b = blockIdx.x;
  const int tid = threadIdx.x;
  const int cnt = min(gCount[b], CAP);
  const int base = coarseBase[b];

  if (tid < 128) hist[tid] = 0;
  __syncthreads();
  for (int j = tid; j < cnt; j += 512) {
    int p = bucketBuf[b * CAP + j];
    raw[j] = p;
    atomicAdd(&hist[p & 127], 1);
  }
  __syncthreads();
  if (tid < 128) sc[tid] = hist[tid];
  __syncthreads();
  for (int off = 1; off < 128; off <<= 1) {
    int t = (tid < 128 && tid >= off) ? sc[tid - off] : 0;
    __syncthreads();
    if (tid < 128 && tid >= off) sc[tid] += t;
    __syncthreads();
  }
  if (tid < 128) {
    bs[tid] = sc[tid] - hist[tid];
    cur[tid] = bs[tid];
    int node = b * 128 + tid;
    if (node < N) rowstart[node] = base + bs[tid];
  }
  __syncthreads();
  for (int j = tid; j < cnt; j += 512) {
    int p = raw[j];
    int pos = atomicAdd(&cur[p & 127], 1);
    srt[pos] = p;
  }
  __syncthreads();
  // packed[e] = src*576 + et*64 (ushort2-unit offset of the y slice)
  for (int j = tid; j < cnt; j += 512) {
    int p = srt[j];
    packed[base + j] = (p >> 10) * 576 + (((p >> 7) & 7) << 6);
  }
}

// ---------------- converts ----------------
__global__ void k_xcast(const float* __restrict__ x, ushort4* __restrict__ xb4,
                        int n4, int npad4) {
  int i = blockIdx.x * 256 + threadIdx.x;
  if (i >= npad4) return;
  ushort4 o = {0, 0, 0, 0};
  if (i < n4) {
    f32x4 v = *(const f32x4*)(x + i * 4);
    __hip_bfloat16 h0 = __float2bfloat16(v[0]), h1 = __float2bfloat16(v[1]);
    __hip_bfloat16 h2 = __float2bfloat16(v[2]), h3 = __float2bfloat16(v[3]);
    o.x = *(unsigned short*)&h0; o.y = *(unsigned short*)&h1;
    o.z = *(unsigned short*)&h2; o.w = *(unsigned short*)&h3;
  }
  xb4[i] = o;
}

// Wb row-major [1152 n][128 k]: n<1024 -> W_w[n>>7][k][n&127], else W_res[k][n&127]
__global__ void k_wb(const float* __restrict__ Ww, const float* __restrict__ Wres,
                     __hip_bfloat16* __restrict__ Wb) {
  int o = blockIdx.x * 256 + threadIdx.x;
  if (o >= KW * 128) return;
  int nn = o >> 7, kk = o & 127;
  float v = (nn < 1024) ? Ww[(nn >> 7) * 16384 + kk * 128 + (nn & 127)]
                        : Wres[kk * 128 + (nn & 127)];
  Wb[o] = __float2bfloat16(v);
}

// ---------------- y GEMM: [padM,128] x [128,1152] -> y bf16 ----------------
// grid (padM/128, 9), 512 threads (8 waves, 2x4), single K=128 shot.
// XOR swizzle ^((row&7)<<4) via pre-swizzled global source + swizzled ds_read.
// y stores are nontemporal: keep A-tiles resident in L2 across the 9 passes.
__global__ __launch_bounds__(512) void k_ygemm(
    const __hip_bfloat16* __restrict__ xb, const __hip_bfloat16* __restrict__ Wb,
    unsigned short* __restrict__ y) {
  __shared__ __align__(16) unsigned short As[128 * 128];
  __shared__ __align__(16) unsigned short Bs[128 * 128];
  const int tid = threadIdx.x;
  const int lane = tid & 63;
  const int wid = tid >> 6;
  const int wr = wid >> 2, wc = wid & 3;  // 2 x 4 waves -> 64x32 per wave
  const long row0 = (long)blockIdx.x * 128;
  const int nb0 = blockIdx.y * 128;

  const char* xbb = (const char*)xb;
  const char* wbb = (const char*)Wb;
  char* asb = (char*)As;
  char* bsb = (char*)Bs;

#pragma unroll
  for (int i = 0; i < 8; ++i) {
    int c = i * 512 + tid;
    int half = c >> 11;  // 0: A, 1: B
    int cc = c & 2047;
    int r = cc >> 4, colb = (cc & 15) << 4;
    int srcb = colb ^ ((r & 7) << 4);
    if (half == 0)
      gload_lds16(xbb + (row0 + r) * 256 + srcb, asb + r * 256 + colb);
    else
      gload_lds16(wbb + (long)(nb0 + r) * 256 + srcb, bsb + r * 256 + colb);
  }
  asm volatile("s_waitcnt vmcnt(0)" ::: "memory");
  __syncthreads();

  f32x4 acc[4][2] = {};
#pragma unroll
  for (int ks = 0; ks < 4; ++ks) {
    const int cb = ks * 64 + ((lane >> 4) << 4);
    bf16x8 af[4], bfr[2];
#pragma unroll
    for (int mi = 0; mi < 4; ++mi) {
      int row = wr * 64 + mi * 16 + (lane & 15);
      af[mi] = *(const bf16x8*)(asb + ((row * 256 + cb) ^ ((row & 7) << 4)));
    }
#pragma unroll
    for (int ni = 0; ni < 2; ++ni) {
      int rowb = wc * 32 + ni * 16 + (lane & 15);
      bfr[ni] = *(const bf16x8*)(bsb + ((rowb * 256 + cb) ^ ((rowb & 7) << 4)));
    }
#pragma unroll
    for (int mi = 0; mi < 4; ++mi)
#pragma unroll
      for (int ni = 0; ni < 2; ++ni)
        acc[mi][ni] = __builtin_amdgcn_mfma_f32_16x16x32_bf16(
            af[mi], bfr[ni], acc[mi][ni], 0, 0, 0);
  }

  // C/D layout: col = lane&15, row = (lane>>4)*4 + q  — nontemporal stores
#pragma unroll
  for (int mi = 0; mi < 4; ++mi)
#pragma unroll
    for (int ni = 0; ni < 2; ++ni) {
      int col = nb0 + wc * 32 + ni * 16 + (lane & 15);
      long rb = row0 + wr * 64 + mi * 16 + ((lane >> 4) << 2);
      f32x4 v = acc[mi][ni];
#pragma unroll
      for (int q = 0; q < 4; ++q) {
        __hip_bfloat16 h = __float2bfloat16(v[q]);
        __builtin_nontemporal_store(*(unsigned short*)&h, y + (rb + q) * KW + col);
      }
    }
}

// ---------------- scatter-sum + residual + bias + ELU ----------------
// 1 wave per node, lane owns cols (2*lane, 2*lane+1); f32 register acc;
// chunk-16 prefetch of coalesced 256B y-row slices, forced in-flight via
// sched_barrier (compiler otherwise serializes to ~2-deep; VGPR_Count 20 -> ~48).
__global__ __launch_bounds__(256) void k_scat(
    const ushort2* __restrict__ y2, const int* __restrict__ rowstart,
    const int* __restrict__ packed, const float* __restrict__ bres,
    float* __restrict__ out, int N) {
  const int w = threadIdx.x >> 6, lane = threadIdx.x & 63;
  const int n = blockIdx.x * 4 + w;
  if (n >= N) return;
  float ax = 0.f, ay = 0.f;
  int e = rowstart[n];
  const int end = rowstart[n + 1];
  for (; e + 16 <= end; e += 16) {
    int p[16];
#pragma unroll
    for (int j = 0; j < 16; ++j) p[j] = packed[e + j];
    ushort2 r[16];
#pragma unroll
    for (int j = 0; j < 16; ++j) r[j] = y2[p[j] + lane];
    __builtin_amdgcn_sched_barrier(0);  // keep all 16 loads issued before adds
#pragma unroll
    for (int j = 0; j < 16; ++j) {
      ax += __uint_as_float((unsigned)r[j].x << 16);
      ay += __uint_as_float((unsigned)r[j].y << 16);
    }
  }
  {
    int p[4];
    ushort2 r[4];
    for (; e + 4 <= end; e += 4) {
#pragma unroll
      for (int j = 0; j < 4; ++j) p[j] = packed[e + j];
#pragma unroll
      for (int j = 0; j < 4; ++j) r[j] = y2[p[j] + lane];
      __builtin_amdgcn_sched_barrier(0);
#pragma unroll
      for (int j = 0; j < 4; ++j) {
        ax += __uint_as_float((unsigned)r[j].x << 16);
        ay += __uint_as_float((unsigned)r[j].y << 16);
      }
    }
  }
  for (; e < end; ++e) {
    ushort2 r = y2[packed[e] + lane];
    ax += __uint_as_float((unsigned)r.x << 16);
    ay += __uint_as_float((unsigned)r.y << 16);
  }
  ushort2 rr = y2[n * 576 + 512 + lane];  // residual slice y[n, 1024..]
  ax += __uint_as_float((unsigned)rr.x << 16) + bres[2 * lane];
  ay += __uint_as_float((unsigned)rr.y << 16) + bres[2 * lane + 1];
  f32x2 o;
  o[0] = ax > 0.f ? ax : (expf(ax) - 1.f);
  o[1] = ay > 0.f ? ay : (expf(ay) - 1.f);
  __builtin_nontemporal_store(o, (f32x2*)(out + (long)n * 128 + 2 * lane));
}

extern "C" void kernel_launch(void* const* d_in, const int* in_sizes, int n_in,
                              void* d_out, int out_size, void* d_ws, size_t ws_size,
                              hipStream_t stream) {
  const float* x = (const float*)d_in[0];
  const int* src = (const int*)d_in[1];
  const int* dst = (const int*)d_in[2];
  const int* et = (const int*)d_in[3];
  const float* Ww = (const float*)d_in[4];
  const float* Wres = (const float*)d_in[7];
  const float* bres = (const float*)d_in[8];
  float* out = (float*)d_out;

  const int N = in_sizes[0] / 128;  // 50000 (< 65536 required by pack26)
  const int E = in_sizes[1];
  const int padM = ((N + 127) / 128) * 128;
  const int COARSE = (N + 127) >> 7;  // 391

  char* ws = (char*)d_ws;
  size_t off = 0;
  auto take = [&](size_t b) {
    char* p = ws + off;
    off = (off + b + 255) & ~(size_t)255;
    return p;
  };
  __hip_bfloat16* y = (__hip_bfloat16*)take((size_t)padM * KW * 2);
  __hip_bfloat16* Wb = (__hip_bfloat16*)take((size_t)KW * 128 * 2);
  __hip_bfloat16* xb = (__hip_bfloat16*)take((size_t)padM * 128 * 2);
  int* rowstart = (int*)take((size_t)(N + 1) * 4);
  int* gCount = (int*)take(512 * 4);
  int* coarseBase = (int*)take(512 * 4);
  int* packed = (int*)take((size_t)E * 4);
  // bucketBuf aliases y: consumed by k_sortB before k_ygemm writes y
  int* bucketBuf = (int*)y;  // COARSE*CAP*4 = 4.8 MB << y's 115 MB

  hipMemsetAsync(gCount, 0, 512 * 4, stream);
  k_binA<<<(E + CHUNK - 1) / CHUNK, 512, 0, stream>>>(src, dst, et, gCount, bucketBuf, E);
  k_scanC<<<1, 512, 0, stream>>>(gCount, coarseBase, rowstart, N, E);
  k_sortB<<<COARSE, 512, 0, stream>>>(bucketBuf, gCount, coarseBase, rowstart, packed, N);
  k_wb<<<(KW * 128 + 255) / 256, 256, 0, stream>>>(Ww, Wres, Wb);
  const int n4 = N * 128 / 4, npad4 = padM * 128 / 4;
  k_xcast<<<(npad4 + 255) / 256, 256, 0, stream>>>(x, (ushort4*)xb, n4, npad4);
  dim3 gy(padM / 128, 9);
  k_ygemm<<<gy, 512, 0, stream>>>(xb, Wb, (unsigned short*)y);
  k_scat<<<(N + 3) / 4, 256, 0, stream>>>((const ushort2*)y, rowstart, packed, bres, out, N);
}

// Round 6
// 198.434 us; speedup vs baseline: 1.1113x; 1.1113x over previous
//
#include <hip/hip_runtime.h>
#include <hip/hip_bf16.h>

// out = elu(segment_sum(typed_linear(x[src], W_w, etype), dst) + x@W_res + b_res)
// (attention path of the reference is dead code)
//
// y = x @ [W_0..W_7, W_res]  ([N,128]x[128,1152] dense MFMA GEMM), then
// out[n] = elu(sum_{e: dst=n} y[src[e], et*128..] + y[n,1024..] + b_res).
// CSR over dst via two-pass LDS counting sort (128-node buckets).

#define KW 1152     // 9*128 columns of y (8 types + residual)
#define CAP 3072    // per-bucket capacity (mean ~2046, ~+22 sigma)
#define CHUNK 2048  // edges per binning block

typedef __bf16 bf16x8 __attribute__((ext_vector_type(8)));
typedef float f32x4 __attribute__((ext_vector_type(4)));

__device__ __forceinline__ void gload_lds16(const void* g, void* l) {
  __builtin_amdgcn_global_load_lds(
      (const __attribute__((address_space(1))) unsigned int*)g,
      (__attribute__((address_space(3))) unsigned int*)l, 16, 0, 0);
}

__device__ __forceinline__ float uflo(unsigned u) { return __uint_as_float(u << 16); }
__device__ __forceinline__ float ufhi(unsigned u) { return __uint_as_float(u & 0xffff0000u); }

// ---------------- CSR pass A: coarse binning by dst>>7 ----------------
// pack26 = (src<<10) | (et<<7) | (dst&127)   (src < 65536, et < 8)
__global__ __launch_bounds__(512) void k_binA(
    const int* __restrict__ src, const int* __restrict__ dst,
    const int* __restrict__ et, int* __restrict__ gCount,
    int* __restrict__ bucketBuf, int E) {
  __shared__ int buf[CHUNK];
  __shared__ short bkt[CHUNK];
  __shared__ int hist[512], sc[512], ls[512], cur[512], gb[512];
  const int tid = threadIdx.x;
  const int base = blockIdx.x * CHUNK;
  const int cnt = min(CHUNK, E - base);

  hist[tid] = 0;
  __syncthreads();
  for (int j = tid; j < cnt; j += 512) atomicAdd(&hist[dst[base + j] >> 7], 1);
  __syncthreads();
  sc[tid] = hist[tid];
  __syncthreads();
  for (int off = 1; off < 512; off <<= 1) {
    int t = (tid >= off) ? sc[tid - off] : 0;
    __syncthreads();
    if (tid >= off) sc[tid] += t;
    __syncthreads();
  }
  ls[tid] = sc[tid] - hist[tid];
  cur[tid] = ls[tid];
  gb[tid] = (hist[tid] > 0) ? atomicAdd(&gCount[tid], hist[tid]) : 0;
  __syncthreads();
  for (int j = tid; j < cnt; j += 512) {
    int e = base + j;
    int d = dst[e];
    int b = d >> 7;
    int pos = atomicAdd(&cur[b], 1);
    buf[pos] = (src[e] << 10) | (et[e] << 7) | (d & 127);
    bkt[pos] = (short)b;
  }
  __syncthreads();
  // bucket-grouped LDS order -> run-wise coalesced global writes
  for (int j = tid; j < cnt; j += 512) {
    int b = bkt[j];
    bucketBuf[b * CAP + gb[b] + (j - ls[b])] = buf[j];
  }
}

// exclusive scan of coarse counts; also rowstart[N] = E
__global__ __launch_bounds__(512) void k_scanC(
    const int* __restrict__ gCount, int* __restrict__ coarseBase,
    int* __restrict__ rowstart, int N, int E) {
  __shared__ int sc[512], h[512];
  int tid = threadIdx.x;
  h[tid] = gCount[tid];
  sc[tid] = h[tid];
  __syncthreads();
  for (int off = 1; off < 512; off <<= 1) {
    int t = (tid >= off) ? sc[tid - off] : 0;
    __syncthreads();
    if (tid >= off) sc[tid] += t;
    __syncthreads();
  }
  coarseBase[tid] = sc[tid] - h[tid];
  if (tid == 0) rowstart[N] = E;
}

// ---------------- CSR pass B: fine sort by dst&127 in LDS ----------------
__global__ __launch_bounds__(512) void k_sortB(
    const int* __restrict__ bucketBuf, const int* __restrict__ gCount,
    const int* __restrict__ coarseBase, int* __restrict__ rowstart,
    int* __restrict__ packed, int N) {
  __shared__ int raw[CAP];
  __shared__ int srt[CAP];
  __shared__ int hist[128], sc[128], bs[128], cur[128];
  const int b = blockIdx.x;
  const int tid = threadIdx.x;
  const int cnt = min(gCount[b], CAP);
  const int base = coarseBase[b];

  if (tid < 128) hist[tid] = 0;
  __syncthreads();
  for (int j = tid; j < cnt; j += 512) {
    int p = bucketBuf[b * CAP + j];
    raw[j] = p;
    atomicAdd(&hist[p & 127], 1);
  }
  __syncthreads();
  if (tid < 128) sc[tid] = hist[tid];
  __syncthreads();
  for (int off = 1; off < 128; off <<= 1) {
    int t = (tid < 128 && tid >= off) ? sc[tid - off] : 0;
    __syncthreads();
    if (tid < 128 && tid >= off) sc[tid] += t;
    __syncthreads();
  }
  if (tid < 128) {
    bs[tid] = sc[tid] - hist[tid];
    cur[tid] = bs[tid];
    int node = b * 128 + tid;
    if (node < N) rowstart[node] = base + bs[tid];
  }
  __syncthreads();
  for (int j = tid; j < cnt; j += 512) {
    int p = raw[j];
    int pos = atomicAdd(&cur[p & 127], 1);
    srt[pos] = p;
  }
  __syncthreads();
  // packed[e] = src*288 + et*32 (ushort4-unit offset of the y slice)
  for (int j = tid; j < cnt; j += 512) {
    int p = srt[j];
    packed[base + j] = (p >> 10) * 288 + (((p >> 7) & 7) << 5);
  }
}

// ---------------- converts ----------------
__global__ void k_xcast(const float* __restrict__ x, ushort4* __restrict__ xb4,
                        int n4, int npad4) {
  int i = blockIdx.x * 256 + threadIdx.x;
  if (i >= npad4) return;
  ushort4 o = {0, 0, 0, 0};
  if (i < n4) {
    f32x4 v = *(const f32x4*)(x + i * 4);
    __hip_bfloat16 h0 = __float2bfloat16(v[0]), h1 = __float2bfloat16(v[1]);
    __hip_bfloat16 h2 = __float2bfloat16(v[2]), h3 = __float2bfloat16(v[3]);
    o.x = *(unsigned short*)&h0; o.y = *(unsigned short*)&h1;
    o.z = *(unsigned short*)&h2; o.w = *(unsigned short*)&h3;
  }
  xb4[i] = o;
}

// Wb row-major [1152 n][128 k]: n<1024 -> W_w[n>>7][k][n&127], else W_res[k][n&127]
__global__ void k_wb(const float* __restrict__ Ww, const float* __restrict__ Wres,
                     __hip_bfloat16* __restrict__ Wb) {
  int o = blockIdx.x * 256 + threadIdx.x;
  if (o >= KW * 128) return;
  int nn = o >> 7, kk = o & 127;
  float v = (nn < 1024) ? Ww[(nn >> 7) * 16384 + kk * 128 + (nn & 127)]
                        : Wres[kk * 128 + (nn & 127)];
  Wb[o] = __float2bfloat16(v);
}

// ---------------- y GEMM: [padM,128] x [128,1152] -> y bf16 ----------------
// grid = padM/128 row tiles; A tile staged ONCE in LDS, then loop over the 9
// 128-col weight groups (B tiles are 288KB total -> always L2-hot).
// XOR swizzle ^((row&7)<<4) via pre-swizzled global source + swizzled ds_read.
__global__ __launch_bounds__(512) void k_ygemm(
    const __hip_bfloat16* __restrict__ xb, const __hip_bfloat16* __restrict__ Wb,
    unsigned short* __restrict__ y) {
  __shared__ __align__(16) unsigned short As[128 * 128];
  __shared__ __align__(16) unsigned short Bs[128 * 128];
  const int tid = threadIdx.x;
  const int lane = tid & 63;
  const int wid = tid >> 6;
  const int wr = wid >> 2, wc = wid & 3;  // 2 x 4 waves -> 64x32 per wave
  const long row0 = (long)blockIdx.x * 128;

  const char* xbb = (const char*)xb;
  const char* wbb = (const char*)Wb;
  char* asb = (char*)As;
  char* bsb = (char*)Bs;

  // stage A once
#pragma unroll
  for (int i = 0; i < 4; ++i) {
    int c = i * 512 + tid;
    int r = c >> 4, colb = (c & 15) << 4;
    int srcb = colb ^ ((r & 7) << 4);
    gload_lds16(xbb + (row0 + r) * 256 + srcb, asb + r * 256 + colb);
  }

  for (int g = 0; g < 9; ++g) {
    // stage B group g
#pragma unroll
    for (int i = 0; i < 4; ++i) {
      int c = i * 512 + tid;
      int r = c >> 4, colb = (c & 15) << 4;
      int srcb = colb ^ ((r & 7) << 4);
      gload_lds16(wbb + (long)(g * 128 + r) * 256 + srcb, bsb + r * 256 + colb);
    }
    asm volatile("s_waitcnt vmcnt(0)" ::: "memory");
    __syncthreads();

    f32x4 acc[4][2] = {};
#pragma unroll
    for (int ks = 0; ks < 4; ++ks) {
      const int cb = ks * 64 + ((lane >> 4) << 4);
      bf16x8 af[4], bfr[2];
#pragma unroll
      for (int mi = 0; mi < 4; ++mi) {
        int row = wr * 64 + mi * 16 + (lane & 15);
        af[mi] = *(const bf16x8*)(asb + ((row * 256 + cb) ^ ((row & 7) << 4)));
      }
#pragma unroll
      for (int ni = 0; ni < 2; ++ni) {
        int rowb = wc * 32 + ni * 16 + (lane & 15);
        bfr[ni] = *(const bf16x8*)(bsb + ((rowb * 256 + cb) ^ ((rowb & 7) << 4)));
      }
#pragma unroll
      for (int mi = 0; mi < 4; ++mi)
#pragma unroll
        for (int ni = 0; ni < 2; ++ni)
          acc[mi][ni] = __builtin_amdgcn_mfma_f32_16x16x32_bf16(
              af[mi], bfr[ni], acc[mi][ni], 0, 0, 0);
    }

    // C/D layout: col = lane&15, row = (lane>>4)*4 + q
#pragma unroll
    for (int mi = 0; mi < 4; ++mi)
#pragma unroll
      for (int ni = 0; ni < 2; ++ni) {
        int col = g * 128 + wc * 32 + ni * 16 + (lane & 15);
        long rb = row0 + wr * 64 + mi * 16 + ((lane >> 4) << 2);
        f32x4 v = acc[mi][ni];
#pragma unroll
        for (int q = 0; q < 4; ++q) {
          __hip_bfloat16 h = __float2bfloat16(v[q]);
          y[(rb + q) * KW + col] = *(unsigned short*)&h;
        }
      }
    __syncthreads();  // Bs reused next group
  }
}

// ---------------- scatter-sum + residual + bias + ELU ----------------
// 1 wave per node; 32 lanes x 8B per edge slice, 2 edges per load instruction
// (lane>>5 selects the edge), 8-deep pipeline = 16 edges in flight; final
// __shfl_xor(32) combines the two lane-halves.
__global__ __launch_bounds__(256) void k_scat(
    const uint2* __restrict__ y4, const int* __restrict__ rowstart,
    const int* __restrict__ packed, const float* __restrict__ bres,
    float* __restrict__ out, int N) {
  const int w = threadIdx.x >> 6, lane = threadIdx.x & 63;
  const int n = blockIdx.x * 4 + w;
  if (n >= N) return;
  const int half = lane >> 5;  // which edge of a pair
  const int sub = lane & 31;   // 8B element within the 256B slice
  f32x4 a = {0.f, 0.f, 0.f, 0.f};
  int e = rowstart[n];
  const int end = rowstart[n + 1];

  for (; e + 16 <= end; e += 16) {
    uint2 r[8];
#pragma unroll
    for (int k = 0; k < 8; ++k) {
      int p = packed[e + 2 * k + half];
      r[k] = y4[p + sub];
    }
    __builtin_amdgcn_sched_barrier(0);  // keep all 8 gathers in flight
#pragma unroll
    for (int k = 0; k < 8; ++k) {
      a[0] += uflo(r[k].x); a[1] += ufhi(r[k].x);
      a[2] += uflo(r[k].y); a[3] += ufhi(r[k].y);
    }
  }
  for (; e + 2 <= end; e += 2) {
    int p = packed[e + half];
    uint2 r = y4[p + sub];
    a[0] += uflo(r.x); a[1] += ufhi(r.x);
    a[2] += uflo(r.y); a[3] += ufhi(r.y);
  }
  if (e < end) {  // single leftover edge: only half 0 contributes
    int p = packed[e];
    uint2 r = y4[p + sub];
    if (!half) {
      a[0] += uflo(r.x); a[1] += ufhi(r.x);
      a[2] += uflo(r.y); a[3] += ufhi(r.y);
    }
  }
#pragma unroll
  for (int i = 0; i < 4; ++i) a[i] += __shfl_xor(a[i], 32);

  uint2 rr = y4[n * 288 + 256 + sub];  // residual slice y[n, 1024..]
  f32x4 b4 = *(const f32x4*)(bres + sub * 4);
  a[0] += uflo(rr.x) + b4[0]; a[1] += ufhi(rr.x) + b4[1];
  a[2] += uflo(rr.y) + b4[2]; a[3] += ufhi(rr.y) + b4[3];
  f32x4 o;
#pragma unroll
  for (int i = 0; i < 4; ++i) o[i] = a[i] > 0.f ? a[i] : (expf(a[i]) - 1.f);
  if (!half)
    __builtin_nontemporal_store(o, (f32x4*)(out + (long)n * 128 + sub * 4));
}

extern "C" void kernel_launch(void* const* d_in, const int* in_sizes, int n_in,
                              void* d_out, int out_size, void* d_ws, size_t ws_size,
                              hipStream_t stream) {
  const float* x = (const float*)d_in[0];
  const int* src = (const int*)d_in[1];
  const int* dst = (const int*)d_in[2];
  const int* et = (const int*)d_in[3];
  const float* Ww = (const float*)d_in[4];
  const float* Wres = (const float*)d_in[7];
  const float* bres = (const float*)d_in[8];
  float* out = (float*)d_out;

  const int N = in_sizes[0] / 128;  // 50000 (< 65536 required by pack26)
  const int E = in_sizes[1];
  const int padM = ((N + 127) / 128) * 128;
  const int COARSE = (N + 127) >> 7;  // 391

  char* ws = (char*)d_ws;
  size_t off = 0;
  auto take = [&](size_t b) {
    char* p = ws + off;
    off = (off + b + 255) & ~(size_t)255;
    return p;
  };
  __hip_bfloat16* y = (__hip_bfloat16*)take((size_t)padM * KW * 2);
  __hip_bfloat16* Wb = (__hip_bfloat16*)take((size_t)KW * 128 * 2);
  __hip_bfloat16* xb = (__hip_bfloat16*)take((size_t)padM * 128 * 2);
  int* rowstart = (int*)take((size_t)(N + 1) * 4);
  int* gCount = (int*)take(512 * 4);
  int* coarseBase = (int*)take(512 * 4);
  int* packed = (int*)take((size_t)E * 4);
  // bucketBuf aliases y: consumed by k_sortB before k_ygemm writes y
  int* bucketBuf = (int*)y;  // COARSE*CAP*4 = 4.8 MB << y's 115 MB

  hipMemsetAsync(gCount, 0, 512 * 4, stream);
  k_binA<<<(E + CHUNK - 1) / CHUNK, 512, 0, stream>>>(src, dst, et, gCount, bucketBuf, E);
  k_scanC<<<1, 512, 0, stream>>>(gCount, coarseBase, rowstart, N, E);
  k_sortB<<<COARSE, 512, 0, stream>>>(bucketBuf, gCount, coarseBase, rowstart, packed, N);
  k_wb<<<(KW * 128 + 255) / 256, 256, 0, stream>>>(Ww, Wres, Wb);
  const int n4 = N * 128 / 4, npad4 = padM * 128 / 4;
  k_xcast<<<(npad4 + 255) / 256, 256, 0, stream>>>(x, (ushort4*)xb, n4, npad4);
  k_ygemm<<<padM / 128, 512, 0, stream>>>(xb, Wb, (unsigned short*)y);
  k_scat<<<(N + 3) / 4, 256, 0, stream>>>((const uint2*)y, rowstart, packed, bres, out, N);
}